// Round 3
// baseline (380.493 us; speedup 1.0000x reference)
//
#include <hip/hip_runtime.h>
#include <hip/hip_cooperative_groups.h>
#include <math.h>

namespace cg = cooperative_groups;

#define IMG 224
#define NR  21   // 7 pool windows x 3 kernel shifts -> distinct clipped ranges per axis

__device__ __forceinline__ void range_lohi(int r, int& lo, int& hi) {
    int py = r / 3, s = (r % 3) - 1;     // shift = ky-1 in {-1,0,1}
    lo = 32 * py + s; hi = lo + 32;
    if (lo < 0) lo = 0;
    if (hi > IMG) hi = IMG;
}

// One cooperative kernel, 6 phases separated by grid.sync().
// 384 blocks x 256 threads; 37.7 KB LDS union -> >=4 blocks/CU capacity,
// so all 384 blocks are co-resident (cooperative launch requirement).
__global__ __launch_bounds__(256, 2) void fused_all(
        const float* __restrict__ x,     const float* __restrict__ dct_w,
        const float* __restrict__ dct_b, const float* __restrict__ fft_w,
        const float* __restrict__ fft_b, const float* __restrict__ fc_w,
        const float* __restrict__ fc_b,  float* __restrict__ out,
        float2* __restrict__ Atab, float* __restrict__ afold,
        float* __restrict__ Dm,    float* __restrict__ wsum3,
        float* __restrict__ meansum, float* __restrict__ wsdct,
        float2* __restrict__ T,    float2* __restrict__ rs2,
        float* __restrict__ PT,    float* __restrict__ fcpart)
{
    cg::grid_group grid = cg::this_grid();
    __shared__ __align__(16) char smem[37664];
    int t = threadIdx.x;
    int blk = blockIdx.x;

    // ================= P0: k0 tables (blk 0..22) + k1 gray sums (23..278) ====
    if (blk < NR) {
        double* c0 = (double*)smem;
        double* s0 = c0 + IMG;
        if (t < IMG) {
            double ang = -2.0 * M_PI * (double)t / (double)IMG;
            c0[t] = cos(ang); s0[t] = sin(ang);
        }
        __syncthreads();
        int lo, hi; range_lohi(blk, lo, hi);
        if (t < IMG) {
            int y = t;
            double sr = 0.0, si = 0.0;
            for (int u = lo; u < hi; ++u) {
                int k = (u * y) % IMG;      // exact phase reduction
                sr += c0[k]; si += s0[k];
            }
            Atab[blk * IMG + y] = make_float2((float)sr, (float)si);
        }
    } else if (blk == NR) {
        for (int i = t; i < NR * 8; i += 256) {
            int r = i / 8, j = i % 8;
            int lo, hi; range_lohi(r, lo, hi);
            double s = 0.0;
            for (int y = lo; y < hi; ++y) {
                double sf = (y + 0.5) / 28.0 - 0.5;      // jax half-pixel sample
                double w = 1.0 - fabs(sf - (double)j);
                if (w < 0.0) w = 0.0;
                double tot = 0.0;
                for (int jj = 0; jj < 8; ++jj) {
                    double wj = 1.0 - fabs(sf - (double)jj);
                    if (wj > 0.0) tot += wj;             // boundary renorm = edge clamp
                }
                s += w / tot;
            }
            afold[i] = (float)s;
        }
    } else if (blk == NR + 1) {
        if (t < 64) {
            int k = t / 8, m = t % 8;
            double v = cos(M_PI * (2.0 * m + 1.0) * k / 16.0) * 0.5;  // sqrt(2/8)=0.5
            if (k == 0) v *= 0.70710678118654752440;
            Dm[t] = (float)v;
        }
        for (int i = t; i < 64 * 9; i += 256) {
            int cout = i / 9, q = i % 9;
            float s = 0.f;
            for (int cin = 0; cin < 3; ++cin) s += dct_w[(cout * 3 + cin) * 9 + q];
            wsum3[i] = s;
        }
    } else if (blk >= 23 && blk < 279) {
        int bb = blk - 23;
        int b = bb >> 3, j = bb & 7;
        float* sm = (float*)smem;
        if (t < 216) {
            const float* pr = x + (size_t)(b * 3 + 0) * IMG * IMG;
            const float* pg = x + (size_t)(b * 3 + 1) * IMG * IMG;
            const float* pb = x + (size_t)(b * 3 + 2) * IMG * IMG;
            float acc = 0.f;
            for (int by = 0; by < 27; ++by) {
                int o = (8 * by + j) * IMG + t;
                acc += 76.245f * pr[o] + 149.685f * pg[o] + 29.07f * pb[o];  // 255*(.299,.587,.114)
            }
            sm[t] = acc;
        }
        __syncthreads();
        if (t < 8) {
            float s = 0.f;
            for (int q = t; q < 216; q += 8) s += sm[q];   // column x === t (mod 8)
            meansum[(b * 8 + j) * 8 + t] = s;
        }
    }
    grid.sync();

    // ================= P1: k3a row DFT (blk 0..335) + k2 dct rects (336..367)
    if (blk < 336) {
        int part = t >> 6;                  // wave id = x-part 0..3
        int lane = t & 63;                  // row within block
        float2* sA = (float2*)smem;         // 37.6 KB; reused as reduction buffer

        for (int i = t; i < NR * IMG; i += 256) sA[i] = Atab[i];
        __syncthreads();

        int row = blk * 64 + lane;          // [0, 21504)
        const float* src = x + (size_t)row * IMG + part * 56;

        float2 acc[NR];
        #pragma unroll
        for (int c = 0; c < NR; ++c) acc[c] = make_float2(0.f, 0.f);

        for (int i = 0; i < 56; i += 4) {
            float4 v = *(const float4*)(src + i);
            #pragma unroll
            for (int c = 0; c < NR; ++c) {
                const float2* ap = &sA[c * IMG + part * 56 + i];   // wave-uniform addr
                float2 a0 = ap[0], a1 = ap[1], a2 = ap[2], a3 = ap[3];
                acc[c].x += v.x * a0.x + v.y * a1.x + v.z * a2.x + v.w * a3.x;
                acc[c].y += v.x * a0.y + v.y * a1.y + v.z * a2.y + v.w * a3.y;
            }
        }

        __syncthreads();                    // everyone done reading sA
        float2* red = sA;                   // 3*64*21 float2 fits
        if (part > 0) {
            float2* dst = red + ((size_t)(part - 1) * 64 + lane) * NR;
            #pragma unroll
            for (int c = 0; c < NR; ++c) dst[c] = acc[c];
        }
        __syncthreads();
        if (part == 0) {
            #pragma unroll
            for (int c = 0; c < NR; ++c) {
                float2 s = acc[c];
                float2 p1 = red[((size_t)0 * 64 + lane) * NR + c];
                float2 p2 = red[((size_t)1 * 64 + lane) * NR + c];
                float2 p3 = red[((size_t)2 * 64 + lane) * NR + c];
                s.x += p1.x + p2.x + p3.x;
                s.y += p1.y + p2.y + p3.y;
                T[(size_t)row * NR + c] = s;
            }
        }
    } else if (blk < 368) {
        int b = blk - 336;
        float* M    = (float*)smem;
        float* dimg = M + 64;
        float* Ds   = dimg + 64;
        float* af   = Ds + 64;
        if (t < 64) { M[t] = meansum[b * 64 + t] * (1.0f / 729.0f); Ds[t] = Dm[t]; }
        if (t < NR * 8) af[t] = afold[t];
        __syncthreads();
        if (t < 64) {                       // dimg = D * M * D^T
            int i = t / 8, l = t % 8;
            float s = 0.f;
            for (int j = 0; j < 8; ++j) {
                float rj = 0.f;
                for (int k = 0; k < 8; ++k) rj += M[j * 8 + k] * Ds[l * 8 + k];
                s += Ds[i * 8 + j] * rj;
            }
            dimg[t] = s;
        }
        __syncthreads();
        for (int p = t; p < NR * NR; p += 256) {   // a_rr^T * dimg * a_cc
            int rr = p / NR, cc = p % NR;
            float s = 0.f;
            for (int j = 0; j < 8; ++j) {
                float rj = 0.f;
                for (int k = 0; k < 8; ++k) rj += dimg[j * 8 + k] * af[cc * 8 + k];
                s += af[rr * 8 + j] * rj;
            }
            wsdct[b * NR * NR + p] = s;
        }
    }
    grid.sync();

    // ================= P2: k3b column fold (blk 0..191) ======================
    if (blk < 192) {
        int bc = blk >> 1, half = blk & 1;
        float2* sT  = (float2*)smem;        // [y_local][cc]   112*21
        float2* sAh = sT + 112 * NR;        // [rr][y_local]   21*112

        const float2* Tbase = T + ((size_t)bc * IMG + half * 112) * NR;
        for (int i = t; i < 112 * NR; i += 256) sT[i] = Tbase[i];
        for (int i = t; i < NR * 112; i += 256) {
            int rr = i / 112, y = i % 112;
            sAh[i] = Atab[rr * IMG + half * 112 + y];
        }
        __syncthreads();

        for (int p = t; p < NR * NR; p += 256) {
            int rr = p / NR, cc = p % NR;
            float re = 0.f, im = 0.f;
            const float2* arow = &sAh[rr * 112];
            for (int y = 0; y < 112; ++y) {
                float2 a  = arow[y];
                float2 tv = sT[y * NR + cc];
                re += a.x * tv.x - a.y * tv.y;
                im += a.x * tv.y + a.y * tv.x;
            }
            rs2[(size_t)blk * NR * NR + p] = make_float2(re, im);
        }
    }
    grid.sync();

    // ================= P3: k4 assemble PT[6272][32] (blk 0..31) ==============
    if (blk < 32) {
        int b = blk;
        float2* RSs = (float2*)smem;                    // 1323 float2 = 10584 B
        float*  WSd = (float*)(smem + 10584);           // 441 f
        float*  sfw = (float*)(smem + 10584 + 1764);    // 3456 f = 13824 B
        float*  sws = (float*)(smem + 10584 + 1764 + 13824); // 576 f
        for (int i = t; i < 3 * NR * NR; i += 256) {
            int cin = i / (NR * NR), p = i % (NR * NR);
            float2 v0 = rs2[((size_t)((b * 3 + cin) * 2 + 0)) * NR * NR + p];
            float2 v1 = rs2[((size_t)((b * 3 + cin) * 2 + 1)) * NR * NR + p];
            RSs[i] = make_float2(v0.x + v1.x, v0.y + v1.y);
        }
        for (int p = t; p < NR * NR; p += 256) WSd[p] = wsdct[b * NR * NR + p];
        for (int i = t; i < 64 * 6 * 9; i += 256) sfw[i] = fft_w[i];
        for (int i = t; i < 64 * 9; i += 256) sws[i] = wsum3[i];
        __syncthreads();

        const float inv = 1.0f / 1024.0f;
        for (int i = t; i < 3136; i += 256) {        // DCT half
            int cout = i / 49, q = i % 49, py = q / 7, px = q % 7;
            float s = 0.f;
            #pragma unroll
            for (int ky = 0; ky < 3; ++ky)
                #pragma unroll
                for (int kx = 0; kx < 3; ++kx)
                    s += sws[cout * 9 + ky * 3 + kx] * WSd[(py * 3 + ky) * NR + (px * 3 + kx)];
            PT[(size_t)i * 32 + b] = dct_b[cout] + s * inv;
        }
        for (int i = t; i < 3136; i += 256) {        // FFT half
            int cout = i / 49, q = i % 49, py = q / 7, px = q % 7;
            float s = 0.f;
            for (int cin = 0; cin < 3; ++cin) {
                #pragma unroll
                for (int ky = 0; ky < 3; ++ky)
                    #pragma unroll
                    for (int kx = 0; kx < 3; ++kx) {
                        float2 v = RSs[cin * NR * NR + (py * 3 + ky) * NR + (px * 3 + kx)];
                        const float* wp = &sfw[(cout * 6 + 2 * cin) * 9 + ky * 3 + kx];
                        s += wp[0] * v.x + wp[9] * v.y;   // real chan, imag chan
                    }
            }
            PT[(size_t)(3136 + i) * 32 + b] = fft_b[cout] + s * inv;
        }
    }
    grid.sync();

    // ================= P4: k5 FC partials, 16-way k-split (blk 0..255) =======
    if (blk < 256) {
        int ot = blk & 15, kc = blk >> 4;
        int b = t & 31, oi = t >> 5;
        int o0 = ot * 32 + oi * 4;
        float a0 = 0.f, a1 = 0.f, a2 = 0.f, a3 = 0.f;
        const float* w0 = fc_w + (size_t)(o0 + 0) * 6272;
        const float* w1 = fc_w + (size_t)(o0 + 1) * 6272;
        const float* w2 = fc_w + (size_t)(o0 + 2) * 6272;
        const float* w3 = fc_w + (size_t)(o0 + 3) * 6272;
        int k0 = kc * 392;
        for (int k = k0; k < k0 + 392; ++k) {
            float p = PT[(size_t)k * 32 + b];
            a0 += p * w0[k]; a1 += p * w1[k]; a2 += p * w2[k]; a3 += p * w3[k];
        }
        fcpart[((size_t)kc * 512 + o0 + 0) * 32 + b] = a0;
        fcpart[((size_t)kc * 512 + o0 + 1) * 32 + b] = a1;
        fcpart[((size_t)kc * 512 + o0 + 2) * 32 + b] = a2;
        fcpart[((size_t)kc * 512 + o0 + 3) * 32 + b] = a3;
    }
    grid.sync();

    // ================= P5: k6 reduce + bias + relu (blk 0..63) ===============
    if (blk < 64) {
        int idx = blk * 256 + t;
        int b = idx >> 9, o = idx & 511;
        float s = fc_b[o];
        for (int c = 0; c < 16; ++c) s += fcpart[((size_t)c * 512 + o) * 32 + b];
        out[(size_t)b * 512 + o] = fmaxf(s, 0.f);
    }
}

extern "C" void kernel_launch(void* const* d_in, const int* in_sizes, int n_in,
                              void* d_out, int out_size, void* d_ws, size_t ws_size,
                              hipStream_t stream)
{
    const float* x     = (const float*)d_in[0];
    const float* dct_w = (const float*)d_in[1];
    const float* dct_b = (const float*)d_in[2];
    const float* fft_w = (const float*)d_in[3];
    const float* fft_b = (const float*)d_in[4];
    const float* fc_w  = (const float*)d_in[5];
    const float* fc_b  = (const float*)d_in[6];
    float* out = (float*)d_out;

    char* ws = (char*)d_ws;
    size_t off = 0;
    auto alloc = [&](size_t bytes) {
        char* p = ws + off;
        off = (off + bytes + 255) & ~(size_t)255;
        return p;
    };
    float2* Atab    = (float2*)alloc((size_t)NR * IMG * 8);        // 37.6 KB
    float*  afold   = (float*) alloc((size_t)NR * 8 * 4);
    float*  Dm      = (float*) alloc(64 * 4);
    float*  wsum3   = (float*) alloc(64 * 9 * 4);
    float*  meansum = (float*) alloc(32 * 64 * 4);
    float*  wsdct   = (float*) alloc((size_t)32 * NR * NR * 4);    // 56 KB
    float2* T       = (float2*)alloc((size_t)21504 * NR * 8);      // 3.61 MB
    float2* rs2     = (float2*)alloc((size_t)192 * NR * NR * 8);   // 677 KB
    float*  PT      = (float*) alloc((size_t)6272 * 32 * 4);       // 803 KB
    float*  fcpart  = (float*) alloc((size_t)16 * 512 * 32 * 4);   // 1 MB
    (void)ws_size; (void)in_sizes; (void)n_in; (void)out_size;

    void* args[] = { (void*)&x, (void*)&dct_w, (void*)&dct_b, (void*)&fft_w,
                     (void*)&fft_b, (void*)&fc_w, (void*)&fc_b, (void*)&out,
                     (void*)&Atab, (void*)&afold, (void*)&Dm, (void*)&wsum3,
                     (void*)&meansum, (void*)&wsdct, (void*)&T, (void*)&rs2,
                     (void*)&PT, (void*)&fcpart };
    hipLaunchCooperativeKernel((const void*)fused_all, dim3(384), dim3(256),
                               args, 0, stream);
}

// Round 4
// 237.796 us; speedup vs baseline: 1.6001x; 1.6001x over previous
//
#include <hip/hip_runtime.h>
#include <math.h>

#define IMG 224
#define NR  21   // 7 pool windows x 3 kernel shifts -> distinct clipped ranges per axis

__device__ __forceinline__ void range_lohi(int r, int& lo, int& hi) {
    int py = r / 3, s = (r % 3) - 1;     // shift = ky-1 in {-1,0,1}
    lo = 32 * py + s; hi = lo + 32;
    if (lo < 0) lo = 0;
    if (hi > IMG) hi = IMG;
}

// Geometric-series closed form: sum_{u=lo}^{lo+len-1} cis(-2*pi*u*y/224).
// c0[k]=cos(2*pi*k/224), s0[k]=-sin(2*pi*k/224)  (i.e. cis(-theta_k)).
__device__ __forceinline__ float2 geom_range(int lo, int len, int y,
                                             const float* c0, const float* s0) {
    if (y == 0) return make_float2((float)len, 0.f);
    int i0 = (lo * y) % IMG;
    int iL = (len * y) % IMG;
    float w0x = c0[i0], w0y = s0[i0];
    float wLx = c0[iL], wLy = s0[iL];
    float w1x = c0[y],  w1y = s0[y];
    // num = w0 * (1 - wL)
    float nx = w0x * (1.f - wLx) + w0y * wLy;
    float ny = w0y * (1.f - wLx) - w0x * wLy;
    // den = 1 - w1
    float dx = 1.f - w1x, dy = -w1y;
    float inv = 1.f / (dx * dx + dy * dy);
    return make_float2((nx * dx + ny * dy) * inv, (ny * dx - nx * dy) * inv);
}

__device__ __forceinline__ void build_cis(float* c0, float* s0, int t) {
    if (t < IMG) {
        double ang = 2.0 * M_PI * (double)t / (double)IMG;
        c0[t] = (float)cos(ang);
        s0[t] = (float)(-sin(ang));
    }
}

// ================= KA: row DFT (blk 0..335) + gray mean-block (336..591) =====
// Row-DFT block: 64 rows, wave w = x-part (56 x each). A built inline (closed
// form) into LDS; A reads in the hot loop are wave-uniform broadcasts.
__global__ __launch_bounds__(256) void ka_rowdft_gray(const float* __restrict__ x,
        float2* __restrict__ T, float* __restrict__ meansum)
{
    __shared__ __align__(16) char smem[39424];
    int t = threadIdx.x;
    int blk = blockIdx.x;

    if (blk < 336) {
        float2* sA = (float2*)smem;            // 21*224 float2 = 37632 B
        float*  c0 = (float*)(smem + 37632);   // 224 f
        float*  s0 = c0 + IMG;                 // 224 f
        build_cis(c0, s0, t);
        __syncthreads();
        for (int i = t; i < NR * IMG; i += 256) {
            int r = i / IMG, y = i % IMG;
            int lo, hi; range_lohi(r, lo, hi);
            sA[i] = geom_range(lo, hi - lo, y, c0, s0);
        }
        __syncthreads();

        int part = t >> 6;                  // wave id = x-part 0..3
        int lane = t & 63;                  // row within block
        int row = blk * 64 + lane;          // [0, 21504)
        const float* src = x + (size_t)row * IMG + part * 56;

        float2 acc[NR];
        #pragma unroll
        for (int c = 0; c < NR; ++c) acc[c] = make_float2(0.f, 0.f);

        for (int i = 0; i < 56; i += 4) {
            float4 v = *(const float4*)(src + i);
            #pragma unroll
            for (int c = 0; c < NR; ++c) {
                const float2* ap = &sA[c * IMG + part * 56 + i];   // wave-uniform addr
                float2 a0 = ap[0], a1 = ap[1], a2 = ap[2], a3 = ap[3];
                acc[c].x += v.x * a0.x + v.y * a1.x + v.z * a2.x + v.w * a3.x;
                acc[c].y += v.x * a0.y + v.y * a1.y + v.z * a2.y + v.w * a3.y;
            }
        }

        __syncthreads();                    // everyone done reading sA
        float2* red = (float2*)smem;        // 3*64*21 float2 = 32256 B, fits in sA
        if (part > 0) {
            float2* dst = red + ((size_t)(part - 1) * 64 + lane) * NR;
            #pragma unroll
            for (int c = 0; c < NR; ++c) dst[c] = acc[c];
        }
        __syncthreads();
        if (part == 0) {
            #pragma unroll
            for (int c = 0; c < NR; ++c) {
                float2 s = acc[c];
                float2 p1 = red[((size_t)0 * 64 + lane) * NR + c];
                float2 p2 = red[((size_t)1 * 64 + lane) * NR + c];
                float2 p3 = red[((size_t)2 * 64 + lane) * NR + c];
                s.x += p1.x + p2.x + p3.x;
                s.y += p1.y + p2.y + p3.y;
                T[(size_t)row * NR + c] = s;
            }
        }
    } else {
        int bb = blk - 336;
        int b = bb >> 3, j = bb & 7;
        float* sm = (float*)smem;
        if (t < 216) {
            const float* pr = x + (size_t)(b * 3 + 0) * IMG * IMG;
            const float* pg = x + (size_t)(b * 3 + 1) * IMG * IMG;
            const float* pb = x + (size_t)(b * 3 + 2) * IMG * IMG;
            float acc = 0.f;
            for (int by = 0; by < 27; ++by) {
                int o = (8 * by + j) * IMG + t;
                acc += 76.245f * pr[o] + 149.685f * pg[o] + 29.07f * pb[o];  // 255*(.299,.587,.114)
            }
            sm[t] = acc;
        }
        __syncthreads();
        if (t < 8) {
            float s = 0.f;
            for (int q = t; q < 216; q += 8) s += sm[q];   // column x === t (mod 8)
            meansum[(b * 8 + j) * 8 + t] = s;
        }
    }
}

// ================= KB: column fold + DCT rects + feature assembly ============
// One block per image b. Accumulates RS[cin][rr][cc] over 2 y-halves x 3 cin
// tiles in LDS, then builds the DCT rect-sums (Dm/afold inline) and writes
// PT[6272][32] (pooled conv features, both branches).
__global__ __launch_bounds__(256) void kb_fold_assemble(
        const float2* __restrict__ T, const float* __restrict__ meansum,
        const float* __restrict__ dct_w, const float* __restrict__ dct_b,
        const float* __restrict__ fft_w, const float* __restrict__ fft_b,
        float* __restrict__ PT)
{
    __shared__ __align__(16) char smem[50016];
    float*  c0  = (float*)smem;                 // [0,896)
    float*  s0  = c0 + IMG;                     // [896,1792)
    float2* sAh = (float2*)(smem + 1792);       // 21*112 f2 = 18816  [1792,20608)
    float2* sT  = (float2*)(smem + 20608);      // 112*21 f2 = 18816  [20608,39424)
    float2* RSs = (float2*)(smem + 39424);      // 3*441 f2 = 10584   [39424,50008)
    // post-phase overlays (reuse sAh/sT region, 37632 B at offset 1792):
    float* WSd  = (float*)(smem + 1792);            // 441 f
    float* Msc  = (float*)(smem + 1792 + 1764);     // 64 f
    float* dimg = Msc + 64;                         // 64 f
    float* Ds   = dimg + 64;                        // 64 f
    float* af   = Ds + 64;                          // 168 f
    float* sfw  = af + 168;                         // 3456 f
    float* sws  = sfw + 3456;                       // 576 f   (total 19332 B < 37632)

    int b = blockIdx.x, t = threadIdx.x;
    build_cis(c0, s0, t);
    for (int i = t; i < 3 * NR * NR; i += 256) RSs[i] = make_float2(0.f, 0.f);

    for (int half = 0; half < 2; ++half) {
        __syncthreads();                       // prior fold done reading sAh
        for (int i = t; i < NR * 112; i += 256) {
            int rr = i / 112, y = half * 112 + (i % 112);
            int lo, hi; range_lohi(rr, lo, hi);
            sAh[i] = geom_range(lo, hi - lo, y, c0, s0);
        }
        for (int cin = 0; cin < 3; ++cin) {
            __syncthreads();                   // prior fold done reading sT; sAh ready
            const float2* Tbase = T + ((size_t)(b * 3 + cin) * IMG + half * 112) * NR;
            for (int i = t; i < 112 * NR; i += 256) sT[i] = Tbase[i];
            __syncthreads();
            for (int p = t; p < NR * NR; p += 256) {
                int rr = p / NR, cc = p % NR;
                float re = 0.f, im = 0.f;
                const float2* arow = &sAh[rr * 112];
                for (int y = 0; y < 112; ++y) {
                    float2 a  = arow[y];
                    float2 tv = sT[y * NR + cc];
                    re += a.x * tv.x - a.y * tv.y;
                    im += a.x * tv.y + a.y * tv.x;
                }
                RSs[cin * NR * NR + p].x += re;    // same thread owns p each pass
                RSs[cin * NR * NR + p].y += im;
            }
        }
    }
    __syncthreads();                           // folds complete; overlay region free

    // ---- inline k2 tables: Dm, afold, meansum scale ----
    if (t < 64) {
        int k = t / 8, m = t % 8;
        double v = cos(M_PI * (2.0 * m + 1.0) * k / 16.0) * 0.5;   // sqrt(2/8)=0.5
        if (k == 0) v *= 0.70710678118654752440;
        Ds[t] = (float)v;
        Msc[t] = meansum[b * 64 + t] * (1.0f / 729.0f);
    }
    if (t >= 64 && t < 64 + NR * 8) {
        int i = t - 64, r = i / 8, j = i % 8;
        int lo, hi; range_lohi(r, lo, hi);
        double s = 0.0;
        for (int y = lo; y < hi; ++y) {
            double sf = (y + 0.5) / 28.0 - 0.5;          // jax half-pixel sample
            double w = 1.0 - fabs(sf - (double)j);
            if (w < 0.0) w = 0.0;
            double tot = 0.0;
            for (int jj = 0; jj < 8; ++jj) {
                double wj = 1.0 - fabs(sf - (double)jj);
                if (wj > 0.0) tot += wj;                 // boundary renorm = edge clamp
            }
            s += w / tot;
        }
        af[i] = (float)s;
    }
    for (int i = t; i < 64 * 6 * 9; i += 256) sfw[i] = fft_w[i];
    for (int i = t; i < 64 * 9; i += 256) {
        int cout = i / 9, q = i % 9;
        float s = 0.f;
        for (int cin = 0; cin < 3; ++cin) s += dct_w[(cout * 3 + cin) * 9 + q];
        sws[i] = s;
    }
    __syncthreads();
    if (t < 64) {                       // dimg = D * M * D^T
        int i = t / 8, l = t % 8;
        float s = 0.f;
        for (int j = 0; j < 8; ++j) {
            float rj = 0.f;
            for (int k = 0; k < 8; ++k) rj += Msc[j * 8 + k] * Ds[l * 8 + k];
            s += Ds[i * 8 + j] * rj;
        }
        dimg[t] = s;
    }
    __syncthreads();
    for (int p = t; p < NR * NR; p += 256) {   // a_rr^T * dimg * a_cc
        int rr = p / NR, cc = p % NR;
        float s = 0.f;
        for (int j = 0; j < 8; ++j) {
            float rj = 0.f;
            for (int k = 0; k < 8; ++k) rj += dimg[j * 8 + k] * af[cc * 8 + k];
            s += af[rr * 8 + j] * rj;
        }
        WSd[p] = s;
    }
    __syncthreads();

    // ---- PT assembly ----
    const float inv = 1.0f / 1024.0f;
    for (int i = t; i < 3136; i += 256) {        // DCT half
        int cout = i / 49, q = i % 49, py = q / 7, px = q % 7;
        float s = 0.f;
        #pragma unroll
        for (int ky = 0; ky < 3; ++ky)
            #pragma unroll
            for (int kx = 0; kx < 3; ++kx)
                s += sws[cout * 9 + ky * 3 + kx] * WSd[(py * 3 + ky) * NR + (px * 3 + kx)];
        PT[(size_t)i * 32 + b] = dct_b[cout] + s * inv;
    }
    for (int i = t; i < 3136; i += 256) {        // FFT half
        int cout = i / 49, q = i % 49, py = q / 7, px = q % 7;
        float s = 0.f;
        for (int cin = 0; cin < 3; ++cin) {
            #pragma unroll
            for (int ky = 0; ky < 3; ++ky)
                #pragma unroll
                for (int kx = 0; kx < 3; ++kx) {
                    float2 v = RSs[cin * NR * NR + (py * 3 + ky) * NR + (px * 3 + kx)];
                    const float* wp = &sfw[(cout * 6 + 2 * cin) * 9 + ky * 3 + kx];
                    s += wp[0] * v.x + wp[9] * v.y;   // real chan, imag chan
                }
        }
        PT[(size_t)(3136 + i) * 32 + b] = fft_b[cout] + s * inv;
    }
}

// ================= KC: FC + bias + relu (fused, 2 outputs per block) =========
__global__ __launch_bounds__(256) void kc_fc(const float* __restrict__ PT,
        const float* __restrict__ fc_w, const float* __restrict__ fc_b,
        float* __restrict__ out)
{
    int o0 = blockIdx.x * 2;
    int t = threadIdx.x;
    int b = t & 31, kc = t >> 5;                 // 8-way k split in block
    const float* w0 = fc_w + (size_t)(o0 + 0) * 6272 + kc * 784;
    const float* w1 = fc_w + (size_t)(o0 + 1) * 6272 + kc * 784;
    const float* p  = PT + (size_t)kc * 784 * 32 + b;
    float a0 = 0.f, a1 = 0.f;
    #pragma unroll 4
    for (int k = 0; k < 784; ++k) {
        float pv = p[k * 32];
        a0 += pv * w0[k]; a1 += pv * w1[k];
    }
    __shared__ float r0[256], r1[256];
    r0[t] = a0; r1[t] = a1;
    __syncthreads();
    if (t < 64) {
        int which = t >> 5, b2 = t & 31;
        const float* r = which ? r1 : r0;
        float s = fc_b[o0 + which];
        #pragma unroll
        for (int c = 0; c < 8; ++c) s += r[c * 32 + b2];
        out[(size_t)b2 * 512 + o0 + which] = fmaxf(s, 0.f);
    }
}

extern "C" void kernel_launch(void* const* d_in, const int* in_sizes, int n_in,
                              void* d_out, int out_size, void* d_ws, size_t ws_size,
                              hipStream_t stream)
{
    const float* x     = (const float*)d_in[0];
    const float* dct_w = (const float*)d_in[1];
    const float* dct_b = (const float*)d_in[2];
    const float* fft_w = (const float*)d_in[3];
    const float* fft_b = (const float*)d_in[4];
    const float* fc_w  = (const float*)d_in[5];
    const float* fc_b  = (const float*)d_in[6];
    float* out = (float*)d_out;

    char* ws = (char*)d_ws;
    size_t off = 0;
    auto alloc = [&](size_t bytes) {
        char* p = ws + off;
        off = (off + bytes + 255) & ~(size_t)255;
        return p;
    };
    float2* T       = (float2*)alloc((size_t)21504 * NR * 8);      // 3.61 MB
    float*  meansum = (float*) alloc(32 * 64 * 4);
    float*  PT      = (float*) alloc((size_t)6272 * 32 * 4);       // 803 KB
    (void)ws_size; (void)in_sizes; (void)n_in; (void)out_size;

    hipLaunchKernelGGL(ka_rowdft_gray,   dim3(592), dim3(256), 0, stream, x, T, meansum);
    hipLaunchKernelGGL(kb_fold_assemble, dim3(32),  dim3(256), 0, stream,
                       T, meansum, dct_w, dct_b, fft_w, fft_b, PT);
    hipLaunchKernelGGL(kc_fc,            dim3(256), dim3(256), 0, stream, PT, fc_w, fc_b, out);
}

// Round 5
// 194.811 us; speedup vs baseline: 1.9531x; 1.2206x over previous
//
#include <hip/hip_runtime.h>
#include <math.h>

#define IMG 224
#define NR  21   // 7 pool windows x 3 kernel shifts -> distinct clipped ranges per axis

__device__ __forceinline__ void range_lohi(int r, int& lo, int& hi) {
    int py = r / 3, s = (r % 3) - 1;     // shift = ky-1 in {-1,0,1}
    lo = 32 * py + s; hi = lo + 32;
    if (lo < 0) lo = 0;
    if (hi > IMG) hi = IMG;
}

// Geometric-series closed form: sum_{u=lo}^{lo+len-1} cis(-2*pi*u*y/224).
// c0[k]=cos(2*pi*k/224), s0[k]=-sin(2*pi*k/224)  (i.e. cis(-theta_k)).
__device__ __forceinline__ float2 geom_range(int lo, int len, int y,
                                             const float* c0, const float* s0) {
    if (y == 0) return make_float2((float)len, 0.f);
    int i0 = (lo * y) % IMG;
    int iL = (len * y) % IMG;
    float w0x = c0[i0], w0y = s0[i0];
    float wLx = c0[iL], wLy = s0[iL];
    float w1x = c0[y],  w1y = s0[y];
    float nx = w0x * (1.f - wLx) + w0y * wLy;
    float ny = w0y * (1.f - wLx) - w0x * wLy;
    float dx = 1.f - w1x, dy = -w1y;
    float inv = 1.f / (dx * dx + dy * dy);
    return make_float2((nx * dx + ny * dy) * inv, (ny * dx - nx * dy) * inv);
}

__device__ __forceinline__ void build_cis(float* c0, float* s0, int t) {
    if (t < IMG) {
        double ang = 2.0 * M_PI * (double)t / (double)IMG;
        c0[t] = (float)cos(ang);
        s0[t] = (float)(-sin(ang));
    }
}

// ===== KA: row DFT (blk 0..335) + gray mean-block (336..591) + tables (592) ==
__global__ __launch_bounds__(256) void ka_rowdft_gray(const float* __restrict__ x,
        const float* __restrict__ dct_w,
        float2* __restrict__ T, float* __restrict__ meansum,
        float* __restrict__ afold_g, float* __restrict__ Dm_g,
        float* __restrict__ wsum3_g)
{
    __shared__ __align__(16) char smem[39424];
    int t = threadIdx.x;
    int blk = blockIdx.x;

    if (blk < 336) {
        float2* sA = (float2*)smem;            // 21*224 float2 = 37632 B
        float*  c0 = (float*)(smem + 37632);   // 224 f
        float*  s0 = c0 + IMG;                 // 224 f
        build_cis(c0, s0, t);
        __syncthreads();
        for (int i = t; i < NR * IMG; i += 256) {
            int r = i / IMG, y = i % IMG;
            int lo, hi; range_lohi(r, lo, hi);
            sA[i] = geom_range(lo, hi - lo, y, c0, s0);
        }
        __syncthreads();

        int part = t >> 6;                  // wave id = x-part 0..3
        int lane = t & 63;                  // row within block
        int row = blk * 64 + lane;          // [0, 21504)
        const float* src = x + (size_t)row * IMG + part * 56;

        float2 acc[NR];
        #pragma unroll
        for (int c = 0; c < NR; ++c) acc[c] = make_float2(0.f, 0.f);

        for (int i = 0; i < 56; i += 4) {
            float4 v = *(const float4*)(src + i);
            #pragma unroll
            for (int c = 0; c < NR; ++c) {
                const float2* ap = &sA[c * IMG + part * 56 + i];   // wave-uniform addr
                float2 a0 = ap[0], a1 = ap[1], a2 = ap[2], a3 = ap[3];
                acc[c].x += v.x * a0.x + v.y * a1.x + v.z * a2.x + v.w * a3.x;
                acc[c].y += v.x * a0.y + v.y * a1.y + v.z * a2.y + v.w * a3.y;
            }
        }

        __syncthreads();                    // everyone done reading sA
        float2* red = (float2*)smem;        // 3*64*21 float2 = 32256 B, fits
        if (part > 0) {
            float2* dst = red + ((size_t)(part - 1) * 64 + lane) * NR;
            #pragma unroll
            for (int c = 0; c < NR; ++c) dst[c] = acc[c];
        }
        __syncthreads();
        if (part == 0) {
            #pragma unroll
            for (int c = 0; c < NR; ++c) {
                float2 s = acc[c];
                float2 p1 = red[((size_t)0 * 64 + lane) * NR + c];
                float2 p2 = red[((size_t)1 * 64 + lane) * NR + c];
                float2 p3 = red[((size_t)2 * 64 + lane) * NR + c];
                s.x += p1.x + p2.x + p3.x;
                s.y += p1.y + p2.y + p3.y;
                T[(size_t)row * NR + c] = s;
            }
        }
    } else if (blk < 592) {
        int bb = blk - 336;
        int b = bb >> 3, j = bb & 7;
        float* sm = (float*)smem;
        if (t < 216) {
            const float* pr = x + (size_t)(b * 3 + 0) * IMG * IMG;
            const float* pg = x + (size_t)(b * 3 + 1) * IMG * IMG;
            const float* pb = x + (size_t)(b * 3 + 2) * IMG * IMG;
            float acc = 0.f;
            for (int by = 0; by < 27; ++by) {
                int o = (8 * by + j) * IMG + t;
                acc += 76.245f * pr[o] + 149.685f * pg[o] + 29.07f * pb[o];  // 255*(.299,.587,.114)
            }
            sm[t] = acc;
        }
        __syncthreads();
        if (t < 8) {
            float s = 0.f;
            for (int q = t; q < 216; q += 8) s += sm[q];   // column x === t (mod 8)
            meansum[(b * 8 + j) * 8 + t] = s;
        }
    } else {
        // tables: afold (fp64), Dm, wsum3
        if (t < NR * 8) {
            int r = t / 8, j = t % 8;
            int lo, hi; range_lohi(r, lo, hi);
            double s = 0.0;
            for (int y = lo; y < hi; ++y) {
                double sf = (y + 0.5) / 28.0 - 0.5;          // jax half-pixel sample
                double w = 1.0 - fabs(sf - (double)j);
                if (w < 0.0) w = 0.0;
                double tot = 0.0;
                for (int jj = 0; jj < 8; ++jj) {
                    double wj = 1.0 - fabs(sf - (double)jj);
                    if (wj > 0.0) tot += wj;                 // boundary renorm = edge clamp
                }
                s += w / tot;
            }
            afold_g[t] = (float)s;
        }
        if (t >= 192 && t < 256) {
            int i = t - 192, k = i / 8, m = i % 8;
            double v = cos(M_PI * (2.0 * m + 1.0) * k / 16.0) * 0.5;   // sqrt(2/8)=0.5
            if (k == 0) v *= 0.70710678118654752440;
            Dm_g[i] = (float)v;
        }
        for (int i = t; i < 64 * 9; i += 256) {
            int cout = i / 9, q = i % 9;
            float s = 0.f;
            for (int cin = 0; cin < 3; ++cin) s += dct_w[(cout * 3 + cin) * 9 + q];
            wsum3_g[i] = s;
        }
    }
}

// ===== KB1: column fold partials. 192 blocks = (b, cin, half). ==============
__global__ __launch_bounds__(256) void kb_fold(const float2* __restrict__ T,
        float2* __restrict__ rs2)
{
    __shared__ __align__(16) char smem[39424];
    float*  c0  = (float*)smem;                 // 224 f
    float*  s0  = c0 + IMG;                     // 224 f
    float2* sAh = (float2*)(smem + 1792);       // 21*112 f2 = 18816
    float2* sT  = (float2*)(smem + 20608);      // 112*21 f2 = 18816

    int blk = blockIdx.x, t = threadIdx.x;
    int b = blk / 6, rem = blk % 6;
    int cin = rem >> 1, half = rem & 1;

    build_cis(c0, s0, t);
    __syncthreads();
    for (int i = t; i < NR * 112; i += 256) {
        int rr = i / 112, y = half * 112 + (i % 112);
        int lo, hi; range_lohi(rr, lo, hi);
        sAh[i] = geom_range(lo, hi - lo, y, c0, s0);
    }
    const float2* Tbase = T + ((size_t)(b * 3 + cin) * IMG + half * 112) * NR;
    for (int i = t; i < 112 * NR; i += 256) sT[i] = Tbase[i];
    __syncthreads();

    float2* dst = rs2 + (size_t)((b * 3 + cin) * 2 + half) * NR * NR;
    for (int p = t; p < NR * NR; p += 256) {
        int rr = p / NR, cc = p % NR;
        float re = 0.f, im = 0.f;
        const float2* arow = &sAh[rr * 112];
        for (int y = 0; y < 112; ++y) {
            float2 a  = arow[y];
            float2 tv = sT[y * NR + cc];
            re += a.x * tv.x - a.y * tv.y;
            im += a.x * tv.y + a.y * tv.x;
        }
        dst[p] = make_float2(re, im);
    }
}

// ===== KB2: assemble PT. 64 blocks = (b, branch). ===========================
__global__ __launch_bounds__(256) void kb_asm(const float2* __restrict__ rs2,
        const float* __restrict__ meansum, const float* __restrict__ afold_g,
        const float* __restrict__ Dm_g, const float* __restrict__ wsum3_g,
        const float* __restrict__ dct_b, const float* __restrict__ fft_w,
        const float* __restrict__ fft_b, float* __restrict__ PT)
{
    __shared__ __align__(16) char smem[24576];
    int blk = blockIdx.x, t = threadIdx.x;
    int b = blk >> 1, which = blk & 1;
    const float inv = 1.0f / 1024.0f;

    if (which == 0) {                 // ---- DCT branch ----
        float* WSd  = (float*)smem;            // 441
        float* Msc  = WSd + 441;               // 64
        float* dimg = Msc + 64;                // 64
        float* Ds   = dimg + 64;               // 64
        float* af   = Ds + 64;                 // 168
        float* sws  = af + 168;                // 576
        if (t < 64) { Ds[t] = Dm_g[t]; Msc[t] = meansum[b * 64 + t] * (1.0f / 729.0f); }
        if (t < NR * 8) af[t] = afold_g[t];
        for (int i = t; i < 64 * 9; i += 256) sws[i] = wsum3_g[i];
        __syncthreads();
        if (t < 64) {                       // dimg = D * M * D^T
            int i = t / 8, l = t % 8;
            float s = 0.f;
            for (int j = 0; j < 8; ++j) {
                float rj = 0.f;
                for (int k = 0; k < 8; ++k) rj += Msc[j * 8 + k] * Ds[l * 8 + k];
                s += Ds[i * 8 + j] * rj;
            }
            dimg[t] = s;
        }
        __syncthreads();
        for (int p = t; p < NR * NR; p += 256) {   // a_rr^T * dimg * a_cc
            int rr = p / NR, cc = p % NR;
            float s = 0.f;
            for (int j = 0; j < 8; ++j) {
                float rj = 0.f;
                for (int k = 0; k < 8; ++k) rj += dimg[j * 8 + k] * af[cc * 8 + k];
                s += af[rr * 8 + j] * rj;
            }
            WSd[p] = s;
        }
        __syncthreads();
        for (int i = t; i < 3136; i += 256) {
            int cout = i / 49, q = i % 49, py = q / 7, px = q % 7;
            float s = 0.f;
            #pragma unroll
            for (int ky = 0; ky < 3; ++ky)
                #pragma unroll
                for (int kx = 0; kx < 3; ++kx)
                    s += sws[cout * 9 + ky * 3 + kx] * WSd[(py * 3 + ky) * NR + (px * 3 + kx)];
            PT[(size_t)i * 32 + b] = dct_b[cout] + s * inv;
        }
    } else {                          // ---- FFT branch ----
        float2* RSs = (float2*)smem;                  // 3*441 f2 = 10584 B
        float*  sfw = (float*)(smem + 10584);         // 3456 f = 13824 B
        for (int i = t; i < 3 * NR * NR; i += 256) {
            int cin = i / (NR * NR), p = i % (NR * NR);
            float2 v0 = rs2[(size_t)((b * 3 + cin) * 2 + 0) * NR * NR + p];
            float2 v1 = rs2[(size_t)((b * 3 + cin) * 2 + 1) * NR * NR + p];
            RSs[i] = make_float2(v0.x + v1.x, v0.y + v1.y);
        }
        for (int i = t; i < 64 * 6 * 9; i += 256) sfw[i] = fft_w[i];
        __syncthreads();
        for (int i = t; i < 3136; i += 256) {
            int cout = i / 49, q = i % 49, py = q / 7, px = q % 7;
            float s = 0.f;
            for (int cin = 0; cin < 3; ++cin) {
                #pragma unroll
                for (int ky = 0; ky < 3; ++ky)
                    #pragma unroll
                    for (int kx = 0; kx < 3; ++kx) {
                        float2 v = RSs[cin * NR * NR + (py * 3 + ky) * NR + (px * 3 + kx)];
                        const float* wp = &sfw[(cout * 6 + 2 * cin) * 9 + ky * 3 + kx];
                        s += wp[0] * v.x + wp[9] * v.y;   // real chan, imag chan
                    }
            }
            PT[(size_t)(3136 + i) * 32 + b] = fft_b[cout] + s * inv;
        }
    }
}

// ===== KC: FC + bias + relu (2 outputs per block) ===========================
__global__ __launch_bounds__(256) void kc_fc(const float* __restrict__ PT,
        const float* __restrict__ fc_w, const float* __restrict__ fc_b,
        float* __restrict__ out)
{
    int o0 = blockIdx.x * 2;
    int t = threadIdx.x;
    int b = t & 31, kc = t >> 5;                 // 8-way k split in block
    const float* w0 = fc_w + (size_t)(o0 + 0) * 6272 + kc * 784;
    const float* w1 = fc_w + (size_t)(o0 + 1) * 6272 + kc * 784;
    const float* p  = PT + (size_t)kc * 784 * 32 + b;
    float a0 = 0.f, a1 = 0.f;
    #pragma unroll 4
    for (int k = 0; k < 784; ++k) {
        float pv = p[k * 32];
        a0 += pv * w0[k]; a1 += pv * w1[k];
    }
    __shared__ float r0[256], r1[256];
    r0[t] = a0; r1[t] = a1;
    __syncthreads();
    if (t < 64) {
        int which = t >> 5, b2 = t & 31;
        const float* r = which ? r1 : r0;
        float s = fc_b[o0 + which];
        #pragma unroll
        for (int c = 0; c < 8; ++c) s += r[c * 32 + b2];
        out[(size_t)b2 * 512 + o0 + which] = fmaxf(s, 0.f);
    }
}

extern "C" void kernel_launch(void* const* d_in, const int* in_sizes, int n_in,
                              void* d_out, int out_size, void* d_ws, size_t ws_size,
                              hipStream_t stream)
{
    const float* x     = (const float*)d_in[0];
    const float* dct_w = (const float*)d_in[1];
    const float* dct_b = (const float*)d_in[2];
    const float* fft_w = (const float*)d_in[3];
    const float* fft_b = (const float*)d_in[4];
    const float* fc_w  = (const float*)d_in[5];
    const float* fc_b  = (const float*)d_in[6];
    float* out = (float*)d_out;

    char* ws = (char*)d_ws;
    size_t off = 0;
    auto alloc = [&](size_t bytes) {
        char* p = ws + off;
        off = (off + bytes + 255) & ~(size_t)255;
        return p;
    };
    float2* T       = (float2*)alloc((size_t)21504 * NR * 8);      // 3.61 MB
    float*  meansum = (float*) alloc(32 * 64 * 4);
    float*  afold_g = (float*) alloc(NR * 8 * 4);
    float*  Dm_g    = (float*) alloc(64 * 4);
    float*  wsum3_g = (float*) alloc(64 * 9 * 4);
    float2* rs2     = (float2*)alloc((size_t)192 * NR * NR * 8);   // 677 KB
    float*  PT      = (float*) alloc((size_t)6272 * 32 * 4);       // 803 KB
    (void)ws_size; (void)in_sizes; (void)n_in; (void)out_size;

    hipLaunchKernelGGL(ka_rowdft_gray, dim3(593), dim3(256), 0, stream,
                       x, dct_w, T, meansum, afold_g, Dm_g, wsum3_g);
    hipLaunchKernelGGL(kb_fold,        dim3(192), dim3(256), 0, stream, T, rs2);
    hipLaunchKernelGGL(kb_asm,         dim3(64),  dim3(256), 0, stream,
                       rs2, meansum, afold_g, Dm_g, wsum3_g, dct_b, fft_w, fft_b, PT);
    hipLaunchKernelGGL(kc_fc,          dim3(256), dim3(256), 0, stream, PT, fc_w, fc_b, out);
}

// Round 6
// 147.004 us; speedup vs baseline: 2.5883x; 1.3252x over previous
//
#include <hip/hip_runtime.h>
#include <math.h>

#define IMG 224
#define NR  21   // 7 pool windows x 3 kernel shifts -> distinct clipped ranges per axis

__device__ __forceinline__ void range_lohi(int r, int& lo, int& hi) {
    int py = r / 3, s = (r % 3) - 1;     // shift = ky-1 in {-1,0,1}
    lo = 32 * py + s; hi = lo + 32;
    if (lo < 0) lo = 0;
    if (hi > IMG) hi = IMG;
}

// Geometric-series closed form: sum_{u=lo}^{lo+len-1} cis(-2*pi*u*y/224).
// c0[k]=cos(2*pi*k/224), s0[k]=-sin(2*pi*k/224)  (i.e. cis(-theta_k)).
__device__ __forceinline__ float2 geom_range(int lo, int len, int y,
                                             const float* c0, const float* s0) {
    if (y == 0) return make_float2((float)len, 0.f);
    int i0 = (lo * y) % IMG;
    int iL = (len * y) % IMG;
    float w0x = c0[i0], w0y = s0[i0];
    float wLx = c0[iL], wLy = s0[iL];
    float w1x = c0[y],  w1y = s0[y];
    float nx = w0x * (1.f - wLx) + w0y * wLy;
    float ny = w0y * (1.f - wLx) - w0x * wLy;
    float dx = 1.f - w1x, dy = -w1y;
    float inv = 1.f / (dx * dx + dy * dy);
    return make_float2((nx * dx + ny * dy) * inv, (ny * dx - nx * dy) * inv);
}

__device__ __forceinline__ void build_cis(float* c0, float* s0, int t) {
    if (t < IMG) {
        double ang = 2.0 * M_PI * (double)t / (double)IMG;
        c0[t] = (float)cos(ang);
        s0[t] = (float)(-sin(ang));
    }
}

// ===== KA: row DFT (blk 0..335) + gray mean-block (336..591) + tables (592) ==
__global__ __launch_bounds__(256) void ka_rowdft_gray(const float* __restrict__ x,
        const float* __restrict__ dct_w,
        float2* __restrict__ T, float* __restrict__ meansum,
        float* __restrict__ afold_g, float* __restrict__ Dm_g,
        float* __restrict__ wsum3_g)
{
    __shared__ __align__(16) char smem[39424];
    int t = threadIdx.x;
    int blk = blockIdx.x;

    if (blk < 336) {
        float2* sA = (float2*)smem;            // 21*224 float2 = 37632 B
        float*  c0 = (float*)(smem + 37632);   // 224 f
        float*  s0 = c0 + IMG;                 // 224 f
        build_cis(c0, s0, t);
        __syncthreads();
        for (int i = t; i < NR * IMG; i += 256) {
            int r = i / IMG, y = i % IMG;
            int lo, hi; range_lohi(r, lo, hi);
            sA[i] = geom_range(lo, hi - lo, y, c0, s0);
        }
        __syncthreads();

        int part = t >> 6;                  // wave id = x-part 0..3
        int lane = t & 63;                  // row within block
        int row = blk * 64 + lane;          // [0, 21504)
        const float* src = x + (size_t)row * IMG + part * 56;

        float2 acc[NR];
        #pragma unroll
        for (int c = 0; c < NR; ++c) acc[c] = make_float2(0.f, 0.f);

        for (int i = 0; i < 56; i += 4) {
            float4 v = *(const float4*)(src + i);
            #pragma unroll
            for (int c = 0; c < NR; ++c) {
                const float2* ap = &sA[c * IMG + part * 56 + i];   // wave-uniform addr
                float2 a0 = ap[0], a1 = ap[1], a2 = ap[2], a3 = ap[3];
                acc[c].x += v.x * a0.x + v.y * a1.x + v.z * a2.x + v.w * a3.x;
                acc[c].y += v.x * a0.y + v.y * a1.y + v.z * a2.y + v.w * a3.y;
            }
        }

        __syncthreads();                    // everyone done reading sA
        float2* red = (float2*)smem;        // 3*64*21 float2 = 32256 B, fits
        if (part > 0) {
            float2* dst = red + ((size_t)(part - 1) * 64 + lane) * NR;
            #pragma unroll
            for (int c = 0; c < NR; ++c) dst[c] = acc[c];
        }
        __syncthreads();
        if (part == 0) {
            #pragma unroll
            for (int c = 0; c < NR; ++c) {
                float2 s = acc[c];
                float2 p1 = red[((size_t)0 * 64 + lane) * NR + c];
                float2 p2 = red[((size_t)1 * 64 + lane) * NR + c];
                float2 p3 = red[((size_t)2 * 64 + lane) * NR + c];
                s.x += p1.x + p2.x + p3.x;
                s.y += p1.y + p2.y + p3.y;
                T[(size_t)row * NR + c] = s;
            }
        }
    } else if (blk < 592) {
        int bb = blk - 336;
        int b = bb >> 3, j = bb & 7;
        float* sm = (float*)smem;
        if (t < 216) {
            const float* pr = x + (size_t)(b * 3 + 0) * IMG * IMG;
            const float* pg = x + (size_t)(b * 3 + 1) * IMG * IMG;
            const float* pb = x + (size_t)(b * 3 + 2) * IMG * IMG;
            float acc = 0.f;
            for (int by = 0; by < 27; ++by) {
                int o = (8 * by + j) * IMG + t;
                acc += 76.245f * pr[o] + 149.685f * pg[o] + 29.07f * pb[o];  // 255*(.299,.587,.114)
            }
            sm[t] = acc;
        }
        __syncthreads();
        if (t < 8) {
            float s = 0.f;
            for (int q = t; q < 216; q += 8) s += sm[q];   // column x === t (mod 8)
            meansum[(b * 8 + j) * 8 + t] = s;
        }
    } else {
        // tables: afold (fp64), Dm, wsum3
        if (t < NR * 8) {
            int r = t / 8, j = t % 8;
            int lo, hi; range_lohi(r, lo, hi);
            double s = 0.0;
            for (int y = lo; y < hi; ++y) {
                double sf = (y + 0.5) / 28.0 - 0.5;          // jax half-pixel sample
                double w = 1.0 - fabs(sf - (double)j);
                if (w < 0.0) w = 0.0;
                double tot = 0.0;
                for (int jj = 0; jj < 8; ++jj) {
                    double wj = 1.0 - fabs(sf - (double)jj);
                    if (wj > 0.0) tot += wj;                 // boundary renorm = edge clamp
                }
                s += w / tot;
            }
            afold_g[t] = (float)s;
        }
        if (t >= 192 && t < 256) {
            int i = t - 192, k = i / 8, m = i % 8;
            double v = cos(M_PI * (2.0 * m + 1.0) * k / 16.0) * 0.5;   // sqrt(2/8)=0.5
            if (k == 0) v *= 0.70710678118654752440;
            Dm_g[i] = (float)v;
        }
        for (int i = t; i < 64 * 9; i += 256) {
            int cout = i / 9, q = i % 9;
            float s = 0.f;
            for (int cin = 0; cin < 3; ++cin) s += dct_w[(cout * 3 + cin) * 9 + q];
            wsum3_g[i] = s;
        }
    }
}

// ===== KB1: column fold partials. 192 blocks = (b, cin, half). ==============
__global__ __launch_bounds__(256) void kb_fold(const float2* __restrict__ T,
        float2* __restrict__ rs2)
{
    __shared__ __align__(16) char smem[39424];
    float*  c0  = (float*)smem;                 // 224 f
    float*  s0  = c0 + IMG;                     // 224 f
    float2* sAh = (float2*)(smem + 1792);       // 21*112 f2 = 18816
    float2* sT  = (float2*)(smem + 20608);      // 112*21 f2 = 18816

    int blk = blockIdx.x, t = threadIdx.x;
    int b = blk / 6, rem = blk % 6;
    int cin = rem >> 1, half = rem & 1;

    build_cis(c0, s0, t);
    __syncthreads();
    for (int i = t; i < NR * 112; i += 256) {
        int rr = i / 112, y = half * 112 + (i % 112);
        int lo, hi; range_lohi(rr, lo, hi);
        sAh[i] = geom_range(lo, hi - lo, y, c0, s0);
    }
    const float2* Tbase = T + ((size_t)(b * 3 + cin) * IMG + half * 112) * NR;
    for (int i = t; i < 112 * NR; i += 256) sT[i] = Tbase[i];
    __syncthreads();

    float2* dst = rs2 + (size_t)((b * 3 + cin) * 2 + half) * NR * NR;
    for (int p = t; p < NR * NR; p += 256) {
        int rr = p / NR, cc = p % NR;
        float re = 0.f, im = 0.f;
        const float2* arow = &sAh[rr * 112];
        for (int y = 0; y < 112; ++y) {
            float2 a  = arow[y];
            float2 tv = sT[y * NR + cc];
            re += a.x * tv.x - a.y * tv.y;
            im += a.x * tv.y + a.y * tv.x;
        }
        dst[p] = make_float2(re, im);
    }
}

// ===== KB2: assemble PT. 64 blocks = (b, branch). ===========================
__global__ __launch_bounds__(256) void kb_asm(const float2* __restrict__ rs2,
        const float* __restrict__ meansum, const float* __restrict__ afold_g,
        const float* __restrict__ Dm_g, const float* __restrict__ wsum3_g,
        const float* __restrict__ dct_b, const float* __restrict__ fft_w,
        const float* __restrict__ fft_b, float* __restrict__ PT)
{
    __shared__ __align__(16) char smem[24576];
    int blk = blockIdx.x, t = threadIdx.x;
    int b = blk >> 1, which = blk & 1;
    const float inv = 1.0f / 1024.0f;

    if (which == 0) {                 // ---- DCT branch ----
        float* WSd  = (float*)smem;            // 441
        float* Msc  = WSd + 441;               // 64
        float* dimg = Msc + 64;                // 64
        float* Ds   = dimg + 64;               // 64
        float* af   = Ds + 64;                 // 168
        float* sws  = af + 168;                // 576
        if (t < 64) { Ds[t] = Dm_g[t]; Msc[t] = meansum[b * 64 + t] * (1.0f / 729.0f); }
        if (t < NR * 8) af[t] = afold_g[t];
        for (int i = t; i < 64 * 9; i += 256) sws[i] = wsum3_g[i];
        __syncthreads();
        if (t < 64) {                       // dimg = D * M * D^T
            int i = t / 8, l = t % 8;
            float s = 0.f;
            for (int j = 0; j < 8; ++j) {
                float rj = 0.f;
                for (int k = 0; k < 8; ++k) rj += Msc[j * 8 + k] * Ds[l * 8 + k];
                s += Ds[i * 8 + j] * rj;
            }
            dimg[t] = s;
        }
        __syncthreads();
        for (int p = t; p < NR * NR; p += 256) {   // a_rr^T * dimg * a_cc
            int rr = p / NR, cc = p % NR;
            float s = 0.f;
            for (int j = 0; j < 8; ++j) {
                float rj = 0.f;
                for (int k = 0; k < 8; ++k) rj += dimg[j * 8 + k] * af[cc * 8 + k];
                s += af[rr * 8 + j] * rj;
            }
            WSd[p] = s;
        }
        __syncthreads();
        for (int i = t; i < 3136; i += 256) {
            int cout = i / 49, q = i % 49, py = q / 7, px = q % 7;
            float s = 0.f;
            #pragma unroll
            for (int ky = 0; ky < 3; ++ky)
                #pragma unroll
                for (int kx = 0; kx < 3; ++kx)
                    s += sws[cout * 9 + ky * 3 + kx] * WSd[(py * 3 + ky) * NR + (px * 3 + kx)];
            PT[(size_t)i * 32 + b] = dct_b[cout] + s * inv;
        }
    } else {                          // ---- FFT branch ----
        float2* RSs = (float2*)smem;                  // 3*441 f2 = 10584 B
        float*  sfw = (float*)(smem + 10584);         // 3456 f = 13824 B
        for (int i = t; i < 3 * NR * NR; i += 256) {
            int cin = i / (NR * NR), p = i % (NR * NR);
            float2 v0 = rs2[(size_t)((b * 3 + cin) * 2 + 0) * NR * NR + p];
            float2 v1 = rs2[(size_t)((b * 3 + cin) * 2 + 1) * NR * NR + p];
            RSs[i] = make_float2(v0.x + v1.x, v0.y + v1.y);
        }
        for (int i = t; i < 64 * 6 * 9; i += 256) sfw[i] = fft_w[i];
        __syncthreads();
        for (int i = t; i < 3136; i += 256) {
            int cout = i / 49, q = i % 49, py = q / 7, px = q % 7;
            float s = 0.f;
            for (int cin = 0; cin < 3; ++cin) {
                #pragma unroll
                for (int ky = 0; ky < 3; ++ky)
                    #pragma unroll
                    for (int kx = 0; kx < 3; ++kx) {
                        float2 v = RSs[cin * NR * NR + (py * 3 + ky) * NR + (px * 3 + kx)];
                        const float* wp = &sfw[(cout * 6 + 2 * cin) * 9 + ky * 3 + kx];
                        s += wp[0] * v.x + wp[9] * v.y;   // real chan, imag chan
                    }
            }
            PT[(size_t)(3136 + i) * 32 + b] = fft_b[cout] + s * inv;
        }
    }
}

// ===== KC: FC partials. 1792 blocks = (o-quad 128) x (k-chunk 14 of 448). ====
// Thread: b = t&31, sub = t>>5 (8 subchunks of 56 k). 4 outputs per block.
// Weight loads are float4 (16B, wave-broadcast, disjoint across blocks -> W
// read exactly once from HBM); PT loads are coalesced and L2-resident.
__global__ __launch_bounds__(256) void kc_fc(const float* __restrict__ PT,
        const float* __restrict__ fc_w, float* __restrict__ part)
{
    int oc = blockIdx.x / 14;            // 0..127
    int kc = blockIdx.x % 14;            // 0..13
    int t = threadIdx.x;
    int b = t & 31, sub = t >> 5;
    int o0 = oc * 4;
    int k0 = kc * 448 + sub * 56;

    const float* w0 = fc_w + (size_t)(o0 + 0) * 6272 + k0;
    const float* w1 = fc_w + (size_t)(o0 + 1) * 6272 + k0;
    const float* w2 = fc_w + (size_t)(o0 + 2) * 6272 + k0;
    const float* w3 = fc_w + (size_t)(o0 + 3) * 6272 + k0;
    const float* p  = PT + (size_t)k0 * 32 + b;

    float a0 = 0.f, a1 = 0.f, a2 = 0.f, a3 = 0.f;
    #pragma unroll 2
    for (int k = 0; k < 56; k += 4) {
        float4 v0 = *(const float4*)(w0 + k);
        float4 v1 = *(const float4*)(w1 + k);
        float4 v2 = *(const float4*)(w2 + k);
        float4 v3 = *(const float4*)(w3 + k);
        float p0 = p[(k + 0) * 32];
        float p1 = p[(k + 1) * 32];
        float p2 = p[(k + 2) * 32];
        float p3 = p[(k + 3) * 32];
        a0 += p0 * v0.x + p1 * v0.y + p2 * v0.z + p3 * v0.w;
        a1 += p0 * v1.x + p1 * v1.y + p2 * v1.z + p3 * v1.w;
        a2 += p0 * v2.x + p1 * v2.y + p2 * v2.z + p3 * v2.w;
        a3 += p0 * v3.x + p1 * v3.y + p2 * v3.z + p3 * v3.w;
    }

    __shared__ float sm[8 * 128];            // [sub][oi][b]
    sm[sub * 128 +  0 + b] = a0;
    sm[sub * 128 + 32 + b] = a1;
    sm[sub * 128 + 64 + b] = a2;
    sm[sub * 128 + 96 + b] = a3;
    __syncthreads();
    if (t < 128) {
        int oi = t >> 5, b2 = t & 31;
        float s = 0.f;
        #pragma unroll
        for (int c = 0; c < 8; ++c) s += sm[c * 128 + oi * 32 + b2];
        part[(size_t)kc * 16384 + (size_t)(o0 + oi) * 32 + b2] = s;
    }
}

// ===== KC2: reduce 14 partials + bias + relu ================================
__global__ __launch_bounds__(256) void kc_out(const float* __restrict__ part,
        const float* __restrict__ fc_b, float* __restrict__ out)
{
    int idx = blockIdx.x * 256 + threadIdx.x;     // 64 blocks -> 16384
    int o = idx >> 5, b = idx & 31;
    float s = fc_b[o];
    #pragma unroll
    for (int c = 0; c < 14; ++c) s += part[(size_t)c * 16384 + idx];
    out[(size_t)b * 512 + o] = fmaxf(s, 0.f);
}

extern "C" void kernel_launch(void* const* d_in, const int* in_sizes, int n_in,
                              void* d_out, int out_size, void* d_ws, size_t ws_size,
                              hipStream_t stream)
{
    const float* x     = (const float*)d_in[0];
    const float* dct_w = (const float*)d_in[1];
    const float* dct_b = (const float*)d_in[2];
    const float* fft_w = (const float*)d_in[3];
    const float* fft_b = (const float*)d_in[4];
    const float* fc_w  = (const float*)d_in[5];
    const float* fc_b  = (const float*)d_in[6];
    float* out = (float*)d_out;

    char* ws = (char*)d_ws;
    size_t off = 0;
    auto alloc = [&](size_t bytes) {
        char* p = ws + off;
        off = (off + bytes + 255) & ~(size_t)255;
        return p;
    };
    float2* T       = (float2*)alloc((size_t)21504 * NR * 8);      // 3.61 MB
    float*  meansum = (float*) alloc(32 * 64 * 4);
    float*  afold_g = (float*) alloc(NR * 8 * 4);
    float*  Dm_g    = (float*) alloc(64 * 4);
    float*  wsum3_g = (float*) alloc(64 * 9 * 4);
    float2* rs2     = (float2*)alloc((size_t)192 * NR * NR * 8);   // 677 KB
    float*  PT      = (float*) alloc((size_t)6272 * 32 * 4);       // 803 KB
    float*  part    = (float*) alloc((size_t)14 * 512 * 32 * 4);   // 918 KB
    (void)ws_size; (void)in_sizes; (void)n_in; (void)out_size;

    hipLaunchKernelGGL(ka_rowdft_gray, dim3(593),  dim3(256), 0, stream,
                       x, dct_w, T, meansum, afold_g, Dm_g, wsum3_g);
    hipLaunchKernelGGL(kb_fold,        dim3(192),  dim3(256), 0, stream, T, rs2);
    hipLaunchKernelGGL(kb_asm,         dim3(64),   dim3(256), 0, stream,
                       rs2, meansum, afold_g, Dm_g, wsum3_g, dct_b, fft_w, fft_b, PT);
    hipLaunchKernelGGL(kc_fc,          dim3(1792), dim3(256), 0, stream, PT, fc_w, part);
    hipLaunchKernelGGL(kc_out,         dim3(64),   dim3(256), 0, stream, part, fc_b, out);
}

// Round 7
// 143.514 us; speedup vs baseline: 2.6513x; 1.0243x over previous
//
#include <hip/hip_runtime.h>
#include <math.h>

#define IMG 224
#define NR  21   // 7 pool windows x 3 kernel shifts -> distinct clipped ranges per axis

__device__ __forceinline__ void range_lohi(int r, int& lo, int& hi) {
    int py = r / 3, s = (r % 3) - 1;     // shift = ky-1 in {-1,0,1}
    lo = 32 * py + s; hi = lo + 32;
    if (lo < 0) lo = 0;
    if (hi > IMG) hi = IMG;
}

// Geometric-series closed form: sum_{u=lo}^{lo+len-1} cis(-2*pi*u*y/224).
// c0[k]=cos(2*pi*k/224), s0[k]=-sin(2*pi*k/224)  (i.e. cis(-theta_k)).
__device__ __forceinline__ float2 geom_range(int lo, int len, int y,
                                             const float* c0, const float* s0) {
    if (y == 0) return make_float2((float)len, 0.f);
    int i0 = (lo * y) % IMG;
    int iL = (len * y) % IMG;
    float w0x = c0[i0], w0y = s0[i0];
    float wLx = c0[iL], wLy = s0[iL];
    float w1x = c0[y],  w1y = s0[y];
    float nx = w0x * (1.f - wLx) + w0y * wLy;
    float ny = w0y * (1.f - wLx) - w0x * wLy;
    float dx = 1.f - w1x, dy = -w1y;
    float inv = 1.f / (dx * dx + dy * dy);
    return make_float2((nx * dx + ny * dy) * inv, (ny * dx - nx * dy) * inv);
}

__device__ __forceinline__ void build_cis(float* c0, float* s0, int t) {
    if (t < IMG) {
        double ang = 2.0 * M_PI * (double)t / (double)IMG;
        c0[t] = (float)cos(ang);
        s0[t] = (float)(-sin(ang));
    }
}

// ===== K0: folded A tables are/aim[21][116] (n in [0,113), pad to 116) ======
__global__ __launch_bounds__(256) void k0_tab(float* __restrict__ are,
                                              float* __restrict__ aim)
{
    __shared__ float c0[IMG], s0[IMG];
    int t = threadIdx.x;
    build_cis(c0, s0, t);
    __syncthreads();
    int r = blockIdx.x;
    int lo, hi; range_lohi(r, lo, hi);
    if (t < 116) {
        float2 a = (t < 113) ? geom_range(lo, hi - lo, t, c0, s0)
                             : make_float2(0.f, 0.f);
        are[r * 116 + t] = a.x;
        aim[r * 116 + t] = a.y;
    }
}

// ===== KA: row DFT (blk 0..335) + gray mean-block (336..591) + tables (592) ==
// Row-DFT uses conjugate symmetry: T[c] = sum_{n=0..112} s[n]*ar[c][n]
// + i*d[n]*ai[c][n], s/d in registers, A via wave-uniform SGPR loads.
// LDS used only for the cross-part reduction.
__global__ __launch_bounds__(256) void ka_rowdft_gray(const float* __restrict__ x,
        const float* __restrict__ dct_w,
        const float* __restrict__ are, const float* __restrict__ aim,
        float2* __restrict__ T, float* __restrict__ meansum,
        float* __restrict__ afold_g, float* __restrict__ Dm_g,
        float* __restrict__ wsum3_g)
{
    __shared__ __align__(16) char smem[32256];
    int t = threadIdx.x;
    int blk = blockIdx.x;

    if (blk < 336) {
        int part = __builtin_amdgcn_readfirstlane((t >> 6) & 3);  // wave-scalar
        int lane = t & 63;
        int row = blk * 64 + lane;                 // [0, 21504)
        const float* src = x + (size_t)row * IMG;
        int base0 = part * 28;                     // n-range [base0, base0+28)

        // s/d fold into registers
        float sv[28], dv[28];
        #pragma unroll
        for (int ci = 0; ci < 7; ++ci) {
            int base = base0 + 4 * ci;
            float4 f = *(const float4*)(src + base);
            float fj[4] = { f.x, f.y, f.z, f.w };
            #pragma unroll
            for (int j = 0; j < 4; ++j) {
                int n = base + j;
                float xm = (n == 0) ? 0.f : src[IMG - n];   // mirror sample
                sv[4 * ci + j] = fj[j] + xm;
                dv[4 * ci + j] = fj[j] - xm;
            }
        }
        float x112 = src[112];                     // used by part 0 only

        float2 acc[NR];
        for (int c = 0; c < NR; ++c) {
            const float* arp = are + c * 116 + base0;   // wave-uniform -> s_load
            const float* aip = aim + c * 116 + base0;
            float re = 0.f, im = 0.f;
            #pragma unroll
            for (int ci = 0; ci < 7; ++ci) {
                float4 a4 = *(const float4*)(arp + 4 * ci);
                float4 b4 = *(const float4*)(aip + 4 * ci);
                re += sv[4*ci+0]*a4.x + sv[4*ci+1]*a4.y + sv[4*ci+2]*a4.z + sv[4*ci+3]*a4.w;
                im += dv[4*ci+0]*b4.x + dv[4*ci+1]*b4.y + dv[4*ci+2]*b4.z + dv[4*ci+3]*b4.w;
            }
            if (part == 0) {                       // n=112 counted once
                re += x112 * arp[112];
                im += x112 * aip[112];
            }
            acc[c] = make_float2(re, im);
        }

        float2* red = (float2*)smem;               // 3*64*21 float2 = 32256 B
        if (part > 0) {
            float2* dst = red + ((size_t)(part - 1) * 64 + lane) * NR;
            #pragma unroll
            for (int c = 0; c < NR; ++c) dst[c] = acc[c];
        }
        __syncthreads();
        if (part == 0) {
            #pragma unroll
            for (int c = 0; c < NR; ++c) {
                float2 s = acc[c];
                float2 p1 = red[((size_t)0 * 64 + lane) * NR + c];
                float2 p2 = red[((size_t)1 * 64 + lane) * NR + c];
                float2 p3 = red[((size_t)2 * 64 + lane) * NR + c];
                s.x += p1.x + p2.x + p3.x;
                s.y += p1.y + p2.y + p3.y;
                T[(size_t)row * NR + c] = s;
            }
        }
    } else if (blk < 592) {
        int bb = blk - 336;
        int b = bb >> 3, j = bb & 7;
        float* sm = (float*)smem;
        if (t < 216) {
            const float* pr = x + (size_t)(b * 3 + 0) * IMG * IMG;
            const float* pg = x + (size_t)(b * 3 + 1) * IMG * IMG;
            const float* pb = x + (size_t)(b * 3 + 2) * IMG * IMG;
            float acc = 0.f;
            for (int by = 0; by < 27; ++by) {
                int o = (8 * by + j) * IMG + t;
                acc += 76.245f * pr[o] + 149.685f * pg[o] + 29.07f * pb[o];  // 255*(.299,.587,.114)
            }
            sm[t] = acc;
        }
        __syncthreads();
        if (t < 8) {
            float s = 0.f;
            for (int q = t; q < 216; q += 8) s += sm[q];   // column x === t (mod 8)
            meansum[(b * 8 + j) * 8 + t] = s;
        }
    } else {
        // tables: afold (fp64), Dm, wsum3
        if (t < NR * 8) {
            int r = t / 8, j = t % 8;
            int lo, hi; range_lohi(r, lo, hi);
            double s = 0.0;
            for (int y = lo; y < hi; ++y) {
                double sf = (y + 0.5) / 28.0 - 0.5;          // jax half-pixel sample
                double w = 1.0 - fabs(sf - (double)j);
                if (w < 0.0) w = 0.0;
                double tot = 0.0;
                for (int jj = 0; jj < 8; ++jj) {
                    double wj = 1.0 - fabs(sf - (double)jj);
                    if (wj > 0.0) tot += wj;                 // boundary renorm = edge clamp
                }
                s += w / tot;
            }
            afold_g[t] = (float)s;
        }
        if (t >= 192 && t < 256) {
            int i = t - 192, k = i / 8, m = i % 8;
            double v = cos(M_PI * (2.0 * m + 1.0) * k / 16.0) * 0.5;   // sqrt(2/8)=0.5
            if (k == 0) v *= 0.70710678118654752440;
            Dm_g[i] = (float)v;
        }
        for (int i = t; i < 64 * 9; i += 256) {
            int cout = i / 9, q = i % 9;
            float s = 0.f;
            for (int cin = 0; cin < 3; ++cin) s += dct_w[(cout * 3 + cin) * 9 + q];
            wsum3_g[i] = s;
        }
    }
}

// ===== KB1: column fold partials. 192 blocks = (b, cin, half). ==============
__global__ __launch_bounds__(256) void kb_fold(const float2* __restrict__ T,
        float2* __restrict__ rs2)
{
    __shared__ __align__(16) char smem[39424];
    float*  c0  = (float*)smem;                 // 224 f
    float*  s0  = c0 + IMG;                     // 224 f
    float2* sAh = (float2*)(smem + 1792);       // 21*112 f2 = 18816
    float2* sT  = (float2*)(smem + 20608);      // 112*21 f2 = 18816

    int blk = blockIdx.x, t = threadIdx.x;
    int b = blk / 6, rem = blk % 6;
    int cin = rem >> 1, half = rem & 1;

    build_cis(c0, s0, t);
    __syncthreads();
    for (int i = t; i < NR * 112; i += 256) {
        int rr = i / 112, y = half * 112 + (i % 112);
        int lo, hi; range_lohi(rr, lo, hi);
        sAh[i] = geom_range(lo, hi - lo, y, c0, s0);
    }
    const float2* Tbase = T + ((size_t)(b * 3 + cin) * IMG + half * 112) * NR;
    for (int i = t; i < 112 * NR; i += 256) sT[i] = Tbase[i];
    __syncthreads();

    float2* dst = rs2 + (size_t)((b * 3 + cin) * 2 + half) * NR * NR;
    for (int p = t; p < NR * NR; p += 256) {
        int rr = p / NR, cc = p % NR;
        float re = 0.f, im = 0.f;
        const float2* arow = &sAh[rr * 112];
        for (int y = 0; y < 112; ++y) {
            float2 a  = arow[y];
            float2 tv = sT[y * NR + cc];
            re += a.x * tv.x - a.y * tv.y;
            im += a.x * tv.y + a.y * tv.x;
        }
        dst[p] = make_float2(re, im);
    }
}

// ===== KB2: assemble PT. 64 blocks = (b, branch). ===========================
__global__ __launch_bounds__(256) void kb_asm(const float2* __restrict__ rs2,
        const float* __restrict__ meansum, const float* __restrict__ afold_g,
        const float* __restrict__ Dm_g, const float* __restrict__ wsum3_g,
        const float* __restrict__ dct_b, const float* __restrict__ fft_w,
        const float* __restrict__ fft_b, float* __restrict__ PT)
{
    __shared__ __align__(16) char smem[24576];
    int blk = blockIdx.x, t = threadIdx.x;
    int b = blk >> 1, which = blk & 1;
    const float inv = 1.0f / 1024.0f;

    if (which == 0) {                 // ---- DCT branch ----
        float* WSd  = (float*)smem;            // 441
        float* Msc  = WSd + 441;               // 64
        float* dimg = Msc + 64;                // 64
        float* Ds   = dimg + 64;               // 64
        float* af   = Ds + 64;                 // 168
        float* sws  = af + 168;                // 576
        if (t < 64) { Ds[t] = Dm_g[t]; Msc[t] = meansum[b * 64 + t] * (1.0f / 729.0f); }
        if (t < NR * 8) af[t] = afold_g[t];
        for (int i = t; i < 64 * 9; i += 256) sws[i] = wsum3_g[i];
        __syncthreads();
        if (t < 64) {                       // dimg = D * M * D^T
            int i = t / 8, l = t % 8;
            float s = 0.f;
            for (int j = 0; j < 8; ++j) {
                float rj = 0.f;
                for (int k = 0; k < 8; ++k) rj += Msc[j * 8 + k] * Ds[l * 8 + k];
                s += Ds[i * 8 + j] * rj;
            }
            dimg[t] = s;
        }
        __syncthreads();
        for (int p = t; p < NR * NR; p += 256) {   // a_rr^T * dimg * a_cc
            int rr = p / NR, cc = p % NR;
            float s = 0.f;
            for (int j = 0; j < 8; ++j) {
                float rj = 0.f;
                for (int k = 0; k < 8; ++k) rj += dimg[j * 8 + k] * af[cc * 8 + k];
                s += af[rr * 8 + j] * rj;
            }
            WSd[p] = s;
        }
        __syncthreads();
        for (int i = t; i < 3136; i += 256) {
            int cout = i / 49, q = i % 49, py = q / 7, px = q % 7;
            float s = 0.f;
            #pragma unroll
            for (int ky = 0; ky < 3; ++ky)
                #pragma unroll
                for (int kx = 0; kx < 3; ++kx)
                    s += sws[cout * 9 + ky * 3 + kx] * WSd[(py * 3 + ky) * NR + (px * 3 + kx)];
            PT[(size_t)i * 32 + b] = dct_b[cout] + s * inv;
        }
    } else {                          // ---- FFT branch ----
        float2* RSs = (float2*)smem;                  // 3*441 f2 = 10584 B
        float*  sfw = (float*)(smem + 10584);         // 3456 f = 13824 B
        for (int i = t; i < 3 * NR * NR; i += 256) {
            int cin = i / (NR * NR), p = i % (NR * NR);
            float2 v0 = rs2[(size_t)((b * 3 + cin) * 2 + 0) * NR * NR + p];
            float2 v1 = rs2[(size_t)((b * 3 + cin) * 2 + 1) * NR * NR + p];
            RSs[i] = make_float2(v0.x + v1.x, v0.y + v1.y);
        }
        for (int i = t; i < 64 * 6 * 9; i += 256) sfw[i] = fft_w[i];
        __syncthreads();
        for (int i = t; i < 3136; i += 256) {
            int cout = i / 49, q = i % 49, py = q / 7, px = q % 7;
            float s = 0.f;
            for (int cin = 0; cin < 3; ++cin) {
                #pragma unroll
                for (int ky = 0; ky < 3; ++ky)
                    #pragma unroll
                    for (int kx = 0; kx < 3; ++kx) {
                        float2 v = RSs[cin * NR * NR + (py * 3 + ky) * NR + (px * 3 + kx)];
                        const float* wp = &sfw[(cout * 6 + 2 * cin) * 9 + ky * 3 + kx];
                        s += wp[0] * v.x + wp[9] * v.y;   // real chan, imag chan
                    }
            }
            PT[(size_t)(3136 + i) * 32 + b] = fft_b[cout] + s * inv;
        }
    }
}

// ===== KC: FC partials. 1792 blocks = (o-quad 128) x (k-chunk 14 of 448). ====
__global__ __launch_bounds__(256) void kc_fc(const float* __restrict__ PT,
        const float* __restrict__ fc_w, float* __restrict__ part)
{
    int oc = blockIdx.x / 14;            // 0..127
    int kc = blockIdx.x % 14;            // 0..13
    int t = threadIdx.x;
    int b = t & 31, sub = t >> 5;
    int o0 = oc * 4;
    int k0 = kc * 448 + sub * 56;

    const float* w0 = fc_w + (size_t)(o0 + 0) * 6272 + k0;
    const float* w1 = fc_w + (size_t)(o0 + 1) * 6272 + k0;
    const float* w2 = fc_w + (size_t)(o0 + 2) * 6272 + k0;
    const float* w3 = fc_w + (size_t)(o0 + 3) * 6272 + k0;
    const float* p  = PT + (size_t)k0 * 32 + b;

    float a0 = 0.f, a1 = 0.f, a2 = 0.f, a3 = 0.f;
    #pragma unroll 2
    for (int k = 0; k < 56; k += 4) {
        float4 v0 = *(const float4*)(w0 + k);
        float4 v1 = *(const float4*)(w1 + k);
        float4 v2 = *(const float4*)(w2 + k);
        float4 v3 = *(const float4*)(w3 + k);
        float p0 = p[(k + 0) * 32];
        float p1 = p[(k + 1) * 32];
        float p2 = p[(k + 2) * 32];
        float p3 = p[(k + 3) * 32];
        a0 += p0 * v0.x + p1 * v0.y + p2 * v0.z + p3 * v0.w;
        a1 += p0 * v1.x + p1 * v1.y + p2 * v1.z + p3 * v1.w;
        a2 += p0 * v2.x + p1 * v2.y + p2 * v2.z + p3 * v2.w;
        a3 += p0 * v3.x + p1 * v3.y + p2 * v3.z + p3 * v3.w;
    }

    __shared__ float sm[8 * 128];            // [sub][oi][b]
    sm[sub * 128 +  0 + b] = a0;
    sm[sub * 128 + 32 + b] = a1;
    sm[sub * 128 + 64 + b] = a2;
    sm[sub * 128 + 96 + b] = a3;
    __syncthreads();
    if (t < 128) {
        int oi = t >> 5, b2 = t & 31;
        float s = 0.f;
        #pragma unroll
        for (int c = 0; c < 8; ++c) s += sm[c * 128 + oi * 32 + b2];
        part[(size_t)kc * 16384 + (size_t)(o0 + oi) * 32 + b2] = s;
    }
}

// ===== KC2: reduce 14 partials + bias + relu ================================
__global__ __launch_bounds__(256) void kc_out(const float* __restrict__ part,
        const float* __restrict__ fc_b, float* __restrict__ out)
{
    int idx = blockIdx.x * 256 + threadIdx.x;     // 64 blocks -> 16384
    int o = idx >> 5, b = idx & 31;
    float s = fc_b[o];
    #pragma unroll
    for (int c = 0; c < 14; ++c) s += part[(size_t)c * 16384 + idx];
    out[(size_t)b * 512 + o] = fmaxf(s, 0.f);
}

extern "C" void kernel_launch(void* const* d_in, const int* in_sizes, int n_in,
                              void* d_out, int out_size, void* d_ws, size_t ws_size,
                              hipStream_t stream)
{
    const float* x     = (const float*)d_in[0];
    const float* dct_w = (const float*)d_in[1];
    const float* dct_b = (const float*)d_in[2];
    const float* fft_w = (const float*)d_in[3];
    const float* fft_b = (const float*)d_in[4];
    const float* fc_w  = (const float*)d_in[5];
    const float* fc_b  = (const float*)d_in[6];
    float* out = (float*)d_out;

    char* ws = (char*)d_ws;
    size_t off = 0;
    auto alloc = [&](size_t bytes) {
        char* p = ws + off;
        off = (off + bytes + 255) & ~(size_t)255;
        return p;
    };
    float2* T       = (float2*)alloc((size_t)21504 * NR * 8);      // 3.61 MB
    float*  are     = (float*) alloc((size_t)NR * 116 * 4);
    float*  aim     = (float*) alloc((size_t)NR * 116 * 4);
    float*  meansum = (float*) alloc(32 * 64 * 4);
    float*  afold_g = (float*) alloc(NR * 8 * 4);
    float*  Dm_g    = (float*) alloc(64 * 4);
    float*  wsum3_g = (float*) alloc(64 * 9 * 4);
    float2* rs2     = (float2*)alloc((size_t)192 * NR * NR * 8);   // 677 KB
    float*  PT      = (float*) alloc((size_t)6272 * 32 * 4);       // 803 KB
    float*  part    = (float*) alloc((size_t)14 * 512 * 32 * 4);   // 918 KB
    (void)ws_size; (void)in_sizes; (void)n_in; (void)out_size;

    hipLaunchKernelGGL(k0_tab,         dim3(21),   dim3(256), 0, stream, are, aim);
    hipLaunchKernelGGL(ka_rowdft_gray, dim3(593),  dim3(256), 0, stream,
                       x, dct_w, are, aim, T, meansum, afold_g, Dm_g, wsum3_g);
    hipLaunchKernelGGL(kb_fold,        dim3(192),  dim3(256), 0, stream, T, rs2);
    hipLaunchKernelGGL(kb_asm,         dim3(64),   dim3(256), 0, stream,
                       rs2, meansum, afold_g, Dm_g, wsum3_g, dct_b, fft_w, fft_b, PT);
    hipLaunchKernelGGL(kc_fc,          dim3(1792), dim3(256), 0, stream, PT, fc_w, part);
    hipLaunchKernelGGL(kc_out,         dim3(64),   dim3(256), 0, stream, part, fc_b, out);
}